// Round 2
// baseline (105.067 us; speedup 1.0000x reference)
//
#include <hip/hip_runtime.h>
#include <hip/hip_bf16.h>
#include <stdint.h>

#define NB 16
#define SLQ 2048
#define SLK 2048
#define DD 64
#define BQ 64
#define BK 64

typedef short s16x8 __attribute__((ext_vector_type(8)));
typedef float f32x4 __attribute__((ext_vector_type(4)));
typedef float f32x2 __attribute__((ext_vector_type(2)));

__device__ __forceinline__ int swzb(int row, int bytecol) {
    // 128B rows; XOR row bits into byte-bit4..6 to spread banks
    return row * 128 + (bytecol ^ ((row & 7) << 4));
}

__device__ __forceinline__ uint16_t f2bf(float f) {
    __bf16 h = (__bf16)f;
    return __builtin_bit_cast(uint16_t, h);
}
__device__ __forceinline__ float bf2f(uint16_t u) {
    uint32_t x = ((uint32_t)u) << 16;
    return __builtin_bit_cast(float, x);
}

__global__ __launch_bounds__(256, 2)
void attn_fwd_kernel(const float* __restrict__ q, const float* __restrict__ k,
                     const float* __restrict__ v, const float* __restrict__ vm,
                     float* __restrict__ out)
{
    __shared__ __align__(16) char lqh[BQ * DD * 2];   // Q hi bf16, swizzled
    __shared__ __align__(16) char lql[BQ * DD * 2];   // Q lo (residual) bf16
    __shared__ __align__(16) char lkh[BK * DD * 2];   // K hi
    __shared__ __align__(16) char lkl[BK * DD * 2];   // K lo
    __shared__ __align__(16) char lvt[DD * BK * 2];   // V^T bf16 [d][key]
    __shared__ __align__(16) char lp [BQ * BK * 2];   // P bf16 [qrow][key]
    __shared__ float lmask[BK];

    const int tid  = threadIdx.x;
    const int lane = tid & 63;
    const int w    = tid >> 6;       // wave 0..3 -> q-row strip
    const int lg   = lane >> 4;      // lane group 0..3
    const int lm   = lane & 15;

    const int b  = blockIdx.y;
    const int qt = blockIdx.x;

    const float* qb = q + ((size_t)b * SLQ + (size_t)qt * BQ) * DD;
    const float* kb = k + (size_t)b * SLK * DD;
    const float* vb = v + (size_t)b * SLK * DD;
    const float* mb = vm + (size_t)b * SLK;

    // ---- stage Q tile (f32 -> bf16 hi + residual lo, swizzled) ----
    #pragma unroll
    for (int it = 0; it < 2; ++it) {
        int c = tid + it * 256;                 // 512 chunks of 8 elems
        int row = c >> 3, col8 = c & 7;
        f32x4 a  = *(const f32x4*)(qb + row * DD + col8 * 8);
        f32x4 bb = *(const f32x4*)(qb + row * DD + col8 * 8 + 4);
        s16x8 h, l;
        #pragma unroll
        for (int j = 0; j < 4; ++j) {
            uint16_t hh = f2bf(a[j]);
            h[j] = (short)hh; l[j] = (short)f2bf(a[j] - bf2f(hh));
            uint16_t hb = f2bf(bb[j]);
            h[4 + j] = (short)hb; l[4 + j] = (short)f2bf(bb[j] - bf2f(hb));
        }
        *(s16x8*)(lqh + swzb(row, col8 * 16)) = h;
        *(s16x8*)(lql + swzb(row, col8 * 16)) = l;
    }
    __syncthreads();

    // Q fragments: A[r=lm][d = kc*32 + lg*8 + j]
    s16x8 qfh[2], qfl[2];
    #pragma unroll
    for (int kc = 0; kc < 2; ++kc) {
        qfh[kc] = *(const s16x8*)(lqh + swzb(w * 16 + lm, kc * 64 + lg * 16));
        qfl[kc] = *(const s16x8*)(lql + swzb(w * 16 + lm, kc * 64 + lg * 16));
    }

    float mrow[4], lrow[4];
    f32x4 oacc[4];
    #pragma unroll
    for (int i = 0; i < 4; ++i) { mrow[i] = -1e30f; lrow[i] = 0.f; }
    #pragma unroll
    for (int d = 0; d < 4; ++d) oacc[d] = (f32x4){0.f, 0.f, 0.f, 0.f};

    for (int kt = 0; kt < SLK / BK; ++kt) {
        __syncthreads();   // previous tile fully consumed
        const float* ks = kb + (size_t)kt * BK * DD;
        const float* vs = vb + (size_t)kt * BK * DD;

        // stage K tile [key][d], hi + lo
        #pragma unroll
        for (int it = 0; it < 2; ++it) {
            int c = tid + it * 256;
            int row = c >> 3, col8 = c & 7;
            f32x4 a  = *(const f32x4*)(ks + row * DD + col8 * 8);
            f32x4 bb = *(const f32x4*)(ks + row * DD + col8 * 8 + 4);
            s16x8 h, l;
            #pragma unroll
            for (int j = 0; j < 4; ++j) {
                uint16_t hh = f2bf(a[j]);
                h[j] = (short)hh; l[j] = (short)f2bf(a[j] - bf2f(hh));
                uint16_t hb = f2bf(bb[j]);
                h[4 + j] = (short)hb; l[4 + j] = (short)f2bf(bb[j] - bf2f(hb));
            }
            *(s16x8*)(lkh + swzb(row, col8 * 16)) = h;
            *(s16x8*)(lkl + swzb(row, col8 * 16)) = l;
        }
        // stage V transposed: lvt[d][key]
        #pragma unroll
        for (int it = 0; it < 8; ++it) {
            int c = tid + it * 256;             // 2048 pairs
            int key = c >> 5, dp = (c & 31) * 2;
            f32x2 a = *(const f32x2*)(vs + key * DD + dp);
            *(uint16_t*)(lvt + swzb(dp,     key * 2)) = f2bf(a[0]);
            *(uint16_t*)(lvt + swzb(dp + 1, key * 2)) = f2bf(a[1]);
        }
        if (tid < BK) lmask[tid] = mb[kt * BK + tid];
        __syncthreads();

        // ---- S = Q K^T (split precision): qh*kh + qh*kl + ql*kh ----
        f32x4 s[4];
        #pragma unroll
        for (int f = 0; f < 4; ++f) s[f] = (f32x4){0.f, 0.f, 0.f, 0.f};
        #pragma unroll
        for (int f = 0; f < 4; ++f) {
            #pragma unroll
            for (int kc = 0; kc < 2; ++kc) {
                s16x8 kfh = *(const s16x8*)(lkh + swzb(f * 16 + lm, kc * 64 + lg * 16));
                s16x8 kfl = *(const s16x8*)(lkl + swzb(f * 16 + lm, kc * 64 + lg * 16));
                s[f] = __builtin_amdgcn_mfma_f32_16x16x32_bf16(qfh[kc], kfh, s[f], 0, 0, 0);
                s[f] = __builtin_amdgcn_mfma_f32_16x16x32_bf16(qfh[kc], kfl, s[f], 0, 0, 0);
                s[f] = __builtin_amdgcn_mfma_f32_16x16x32_bf16(qfl[kc], kfh, s[f], 0, 0, 0);
            }
        }

        // ---- mask + online softmax (rows = lg*4+i, cols across lm & f) ----
        float mv[4];
        #pragma unroll
        for (int f = 0; f < 4; ++f) mv[f] = lmask[f * 16 + lm];

        float pmax[4];
        #pragma unroll
        for (int i = 0; i < 4; ++i) {
            float x = -1e30f;
            #pragma unroll
            for (int f = 0; f < 4; ++f) {
                float sv = (mv[f] != 0.f) ? s[f][i] : -1e30f;
                s[f][i] = sv;
                x = fmaxf(x, sv);
            }
            #pragma unroll
            for (int off = 1; off < 16; off <<= 1)
                x = fmaxf(x, __shfl_xor(x, off, 64));
            pmax[i] = x;
        }

        float scl[4];
        #pragma unroll
        for (int i = 0; i < 4; ++i) {
            float mn = fmaxf(mrow[i], pmax[i]);
            scl[i] = __expf(mrow[i] - mn);
            mrow[i] = mn;
        }
        float rs[4] = {0.f, 0.f, 0.f, 0.f};
        #pragma unroll
        for (int f = 0; f < 4; ++f) {
            #pragma unroll
            for (int i = 0; i < 4; ++i) {
                float p = __expf(s[f][i] - mrow[i]);
                s[f][i] = p;
                rs[i] += p;
            }
        }
        #pragma unroll
        for (int i = 0; i < 4; ++i) {
            #pragma unroll
            for (int off = 1; off < 16; off <<= 1)
                rs[i] += __shfl_xor(rs[i], off, 64);
            lrow[i] = lrow[i] * scl[i] + rs[i];
        }
        #pragma unroll
        for (int d = 0; d < 4; ++d)
            #pragma unroll
            for (int i = 0; i < 4; ++i)
                oacc[d][i] *= scl[i];

        // ---- P -> LDS (bf16), wave-private region ----
        #pragma unroll
        for (int f = 0; f < 4; ++f)
            #pragma unroll
            for (int i = 0; i < 4; ++i)
                *(uint16_t*)(lp + swzb(w * 16 + lg * 4 + i, (f * 16 + lm) * 2)) = f2bf(s[f][i]);
        __syncthreads();   // ordering safety for P round-trip

        // ---- O += P V : A=P[r=lm][key], B=V^T rows=d ----
        #pragma unroll
        for (int kc = 0; kc < 2; ++kc) {
            s16x8 pf = *(const s16x8*)(lp + swzb(w * 16 + lm, kc * 64 + lg * 16));
            #pragma unroll
            for (int d = 0; d < 4; ++d) {
                s16x8 vf = *(const s16x8*)(lvt + swzb(d * 16 + lm, kc * 64 + lg * 16));
                oacc[d] = __builtin_amdgcn_mfma_f32_16x16x32_bf16(pf, vf, oacc[d], 0, 0, 0);
            }
        }
    }

    // ---- epilogue: normalize and store f32 ----
    float* ob = out + ((size_t)b * SLQ + (size_t)qt * BQ) * DD;
    #pragma unroll
    for (int i = 0; i < 4; ++i) {
        float inv = 1.f / (lrow[i] + 1e-13f);
        int row = w * 16 + lg * 4 + i;
        #pragma unroll
        for (int d = 0; d < 4; ++d)
            ob[row * DD + d * 16 + lm] = oacc[d][i] * inv;
    }
}

extern "C" void kernel_launch(void* const* d_in, const int* in_sizes, int n_in,
                              void* d_out, int out_size, void* d_ws, size_t ws_size,
                              hipStream_t stream) {
    const float* q  = (const float*)d_in[0];
    const float* k  = (const float*)d_in[1];
    const float* v  = (const float*)d_in[2];
    const float* vm = (const float*)d_in[3];
    float* out = (float*)d_out;
    dim3 grid(SLQ / BQ, NB);
    attn_fwd_kernel<<<grid, dim3(256), 0, stream>>>(q, k, v, vm, out);
}

// Round 3
// 82.337 us; speedup vs baseline: 1.2761x; 1.2761x over previous
//
#include <hip/hip_runtime.h>
#include <hip/hip_bf16.h>
#include <stdint.h>

#define NB 16
#define SLQ 2048
#define SLK 2048
#define DD 64
#define BQ 64
#define BK 64
#define NT (SLK / BK)

typedef _Float16 f16x8 __attribute__((ext_vector_type(8)));
typedef short s16x8 __attribute__((ext_vector_type(8)));
typedef float f32x4 __attribute__((ext_vector_type(4)));
typedef float f32x2 __attribute__((ext_vector_type(2)));

typedef __attribute__((address_space(1))) const void gvoid;
typedef __attribute__((address_space(3))) void lvoid;

__device__ __forceinline__ int swzb(int row, int bytecol) {
    // 128B rows; XOR row bits into byte-bit4..6 to spread banks
    return row * 128 + (bytecol ^ ((row & 7) << 4));
}

__device__ __forceinline__ void gload16(const void* g, void* l) {
    __builtin_amdgcn_global_load_lds((gvoid*)g, (lvoid*)l, 16, 0, 0);
}

// ---------------- pre-pass: f32 -> fp16, tile-contiguous, inverse-swizzled ----------------
// Tiles of 64 rows x 64 cols; out[tile*8192 + row*128 + (col16B ^ ((row&7)<<4))] = in[row][col]
__global__ __launch_bounds__(256) void prep_qk(const float* __restrict__ q,
                                               const float* __restrict__ k,
                                               char* __restrict__ qs,
                                               char* __restrict__ ks) {
    const int tl = blockIdx.x & 511;
    const float* src = (blockIdx.x < 512 ? q : k) + (size_t)tl * (BK * DD);
    char* dst = (blockIdx.x < 512 ? qs : ks) + (size_t)tl * (BK * DD * 2);
    #pragma unroll
    for (int it = 0; it < 2; ++it) {
        int c = threadIdx.x + it * 256;
        int row = c >> 3, col8 = c & 7;
        f32x4 a  = *(const f32x4*)(src + row * DD + col8 * 8);
        f32x4 b2 = *(const f32x4*)(src + row * DD + col8 * 8 + 4);
        f16x8 h;
        #pragma unroll
        for (int j = 0; j < 4; ++j) { h[j] = (_Float16)a[j]; h[4 + j] = (_Float16)b2[j]; }
        *(f16x8*)(dst + swzb(row, col8 * 16)) = h;
    }
}

// V transpose: out tile = [d=64 rows][key 64 cols] fp16, same swizzle. Coalesced row reads.
__global__ __launch_bounds__(256) void prep_v(const float* __restrict__ v,
                                              char* __restrict__ vts) {
    const int tl = blockIdx.x;                 // 0..511
    const float* src = v + (size_t)tl * (BK * DD);
    char* dst = vts + (size_t)tl * (BK * DD * 2);
    const int d = threadIdx.x & 63;
    #pragma unroll
    for (int it = 0; it < 2; ++it) {
        int key8 = (threadIdx.x >> 6) + it * 4;  // 0..7
        f16x8 h;
        #pragma unroll
        for (int j = 0; j < 8; ++j)
            h[j] = (_Float16)src[(key8 * 8 + j) * DD + d];
        *(f16x8*)(dst + swzb(d, key8 * 16)) = h;
    }
}

// ---------------- main flash-attention kernel (fp16 MFMA) ----------------
__global__ __launch_bounds__(256, 2)
void attn_fwd(const char* __restrict__ qs, const char* __restrict__ ks,
              const char* __restrict__ vts, const float* __restrict__ vm,
              float* __restrict__ out)
{
    __shared__ __align__(16) char lp[BQ * DD * 2];        // Q stage, then P
    __shared__ __align__(16) char lk[2][BK * DD * 2];
    __shared__ __align__(16) char lv[2][BK * DD * 2];

    const int tid  = threadIdx.x;
    const int lane = tid & 63;
    const int w    = tid >> 6;
    const int lg   = lane >> 4;
    const int lm   = lane & 15;

    int wg = blockIdx.x;
    wg = (wg & 7) * 64 + (wg >> 3);            // XCD-chunked swizzle (512 % 8 == 0)
    const int b = wg >> 5, qt = wg & 31;

    const char* qtile = qs  + (size_t)(b * 32 + qt) * 8192;
    const char* kbase = ks  + (size_t)b * 32 * 8192;
    const char* vbase = vts + (size_t)b * 32 * 8192;
    const float* mb   = vm  + (size_t)b * SLK;

    // prologue: stage Q (into lp) + tile 0 K/V
    #pragma unroll
    for (int i = 0; i < 2; ++i) {
        int ch = w * 2 + i;
        gload16(qtile + ch * 1024 + lane * 16, lp + ch * 1024);
    }
    #pragma unroll
    for (int i = 0; i < 2; ++i) {
        int ch = w * 2 + i;
        gload16(kbase + ch * 1024 + lane * 16, lk[0] + ch * 1024);
        gload16(vbase + ch * 1024 + lane * 16, lv[0] + ch * 1024);
    }
    asm volatile("s_waitcnt vmcnt(0)" ::: "memory");
    __syncthreads();

    f16x8 qf[2];
    #pragma unroll
    for (int kc = 0; kc < 2; ++kc)
        qf[kc] = *(const f16x8*)(lp + swzb(w * 16 + lm, kc * 64 + lg * 16));

    float mrow[4], lrow[4];
    f32x4 oacc[4];
    #pragma unroll
    for (int i = 0; i < 4; ++i) { mrow[i] = -1e30f; lrow[i] = 0.f; }
    #pragma unroll
    for (int d = 0; d < 4; ++d) oacc[d] = (f32x4){0.f, 0.f, 0.f, 0.f};

    int buf = 0;
    for (int kt = 0; kt < NT; ++kt) {
        // mask loads FIRST (so their vmcnt wait doesn't drain the prefetch)
        float mv[4];
        #pragma unroll
        for (int f = 0; f < 4; ++f) mv[f] = mb[kt * BK + f * 16 + lm];

        // prefetch next tile into other buffer
        if (kt + 1 < NT) {
            const char* kg = kbase + (size_t)(kt + 1) * 8192;
            const char* vg = vbase + (size_t)(kt + 1) * 8192;
            #pragma unroll
            for (int i = 0; i < 2; ++i) {
                int ch = w * 2 + i;
                gload16(kg + ch * 1024 + lane * 16, lk[buf ^ 1] + ch * 1024);
                gload16(vg + ch * 1024 + lane * 16, lv[buf ^ 1] + ch * 1024);
            }
        }

        // ---- S = Q K^T ----
        f32x4 s[4];
        #pragma unroll
        for (int f = 0; f < 4; ++f) s[f] = (f32x4){0.f, 0.f, 0.f, 0.f};
        #pragma unroll
        for (int f = 0; f < 4; ++f) {
            #pragma unroll
            for (int kc = 0; kc < 2; ++kc) {
                f16x8 kf = *(const f16x8*)(lk[buf] + swzb(f * 16 + lm, kc * 64 + lg * 16));
                s[f] = __builtin_amdgcn_mfma_f32_16x16x32_f16(qf[kc], kf, s[f], 0, 0, 0);
            }
        }

        // ---- mask + online softmax ----
        float pmax[4];
        #pragma unroll
        for (int i = 0; i < 4; ++i) {
            float x = -1e30f;
            #pragma unroll
            for (int f = 0; f < 4; ++f) {
                float sv = (mv[f] != 0.f) ? s[f][i] : -1e30f;
                s[f][i] = sv;
                x = fmaxf(x, sv);
            }
            #pragma unroll
            for (int off = 1; off < 16; off <<= 1)
                x = fmaxf(x, __shfl_xor(x, off, 64));
            pmax[i] = x;
        }

        float scl[4];
        #pragma unroll
        for (int i = 0; i < 4; ++i) {
            float mn = fmaxf(mrow[i], pmax[i]);
            scl[i] = __expf(mrow[i] - mn);
            mrow[i] = mn;
        }
        float rs[4] = {0.f, 0.f, 0.f, 0.f};
        #pragma unroll
        for (int f = 0; f < 4; ++f) {
            #pragma unroll
            for (int i = 0; i < 4; ++i) {
                float p = __expf(s[f][i] - mrow[i]);
                s[f][i] = p;
                rs[i] += p;
            }
        }
        #pragma unroll
        for (int i = 0; i < 4; ++i) {
            #pragma unroll
            for (int off = 1; off < 16; off <<= 1)
                rs[i] += __shfl_xor(rs[i], off, 64);
            lrow[i] = lrow[i] * scl[i] + rs[i];
        }
        #pragma unroll
        for (int d = 0; d < 4; ++d)
            #pragma unroll
            for (int i = 0; i < 4; ++i)
                oacc[d][i] *= scl[i];

        // ---- P -> LDS (fp16), wave-private rows ----
        #pragma unroll
        for (int f = 0; f < 4; ++f)
            #pragma unroll
            for (int i = 0; i < 4; ++i) {
                _Float16 ph = (_Float16)s[f][i];
                *(uint16_t*)(lp + swzb(w * 16 + lg * 4 + i, (f * 16 + lm) * 2)) =
                    __builtin_bit_cast(uint16_t, ph);
            }

        // ---- O += P V ----
        #pragma unroll
        for (int kc = 0; kc < 2; ++kc) {
            f16x8 pf = *(const f16x8*)(lp + swzb(w * 16 + lm, kc * 64 + lg * 16));
            #pragma unroll
            for (int d = 0; d < 4; ++d) {
                f16x8 vf = *(const f16x8*)(lv[buf] + swzb(d * 16 + lm, kc * 64 + lg * 16));
                oacc[d] = __builtin_amdgcn_mfma_f32_16x16x32_f16(pf, vf, oacc[d], 0, 0, 0);
            }
        }

        asm volatile("s_waitcnt vmcnt(0)" ::: "memory");
        __syncthreads();
        buf ^= 1;
    }

    // ---- epilogue ----
    float* ob = out + ((size_t)b * SLQ + (size_t)qt * BQ) * DD;
    #pragma unroll
    for (int i = 0; i < 4; ++i) {
        float inv = 1.f / (lrow[i] + 1e-13f);
        int row = w * 16 + lg * 4 + i;
        #pragma unroll
        for (int d = 0; d < 4; ++d)
            ob[row * DD + d * 16 + lm] = oacc[d][i] * inv;
    }
}

// ---------------- fallback (round-2 proven kernel, used if ws too small) ----------------
__device__ __forceinline__ uint16_t f2bf(float f) {
    __bf16 h = (__bf16)f;
    return __builtin_bit_cast(uint16_t, h);
}
__device__ __forceinline__ float bf2f(uint16_t u) {
    uint32_t x = ((uint32_t)u) << 16;
    return __builtin_bit_cast(float, x);
}

__global__ __launch_bounds__(256, 2)
void attn_fallback(const float* __restrict__ q, const float* __restrict__ k,
                   const float* __restrict__ v, const float* __restrict__ vm,
                   float* __restrict__ out)
{
    __shared__ __align__(16) char lqh[BQ * DD * 2];
    __shared__ __align__(16) char lql[BQ * DD * 2];
    __shared__ __align__(16) char lkh[BK * DD * 2];
    __shared__ __align__(16) char lkl[BK * DD * 2];
    __shared__ __align__(16) char lvt[DD * BK * 2];
    __shared__ __align__(16) char lp [BQ * BK * 2];
    __shared__ float lmask[BK];

    const int tid  = threadIdx.x;
    const int lane = tid & 63;
    const int w    = tid >> 6;
    const int lg   = lane >> 4;
    const int lm   = lane & 15;

    const int b  = blockIdx.y;
    const int qt = blockIdx.x;

    const float* qb = q + ((size_t)b * SLQ + (size_t)qt * BQ) * DD;
    const float* kb = k + (size_t)b * SLK * DD;
    const float* vb = v + (size_t)b * SLK * DD;
    const float* mb = vm + (size_t)b * SLK;

    #pragma unroll
    for (int it = 0; it < 2; ++it) {
        int c = tid + it * 256;
        int row = c >> 3, col8 = c & 7;
        f32x4 a  = *(const f32x4*)(qb + row * DD + col8 * 8);
        f32x4 bb = *(const f32x4*)(qb + row * DD + col8 * 8 + 4);
        s16x8 h, l;
        #pragma unroll
        for (int j = 0; j < 4; ++j) {
            uint16_t hh = f2bf(a[j]);
            h[j] = (short)hh; l[j] = (short)f2bf(a[j] - bf2f(hh));
            uint16_t hb = f2bf(bb[j]);
            h[4 + j] = (short)hb; l[4 + j] = (short)f2bf(bb[j] - bf2f(hb));
        }
        *(s16x8*)(lqh + swzb(row, col8 * 16)) = h;
        *(s16x8*)(lql + swzb(row, col8 * 16)) = l;
    }
    __syncthreads();

    s16x8 qfh[2], qfl[2];
    #pragma unroll
    for (int kc = 0; kc < 2; ++kc) {
        qfh[kc] = *(const s16x8*)(lqh + swzb(w * 16 + lm, kc * 64 + lg * 16));
        qfl[kc] = *(const s16x8*)(lql + swzb(w * 16 + lm, kc * 64 + lg * 16));
    }

    float mrow[4], lrow[4];
    f32x4 oacc[4];
    #pragma unroll
    for (int i = 0; i < 4; ++i) { mrow[i] = -1e30f; lrow[i] = 0.f; }
    #pragma unroll
    for (int d = 0; d < 4; ++d) oacc[d] = (f32x4){0.f, 0.f, 0.f, 0.f};

    for (int kt = 0; kt < NT; ++kt) {
        __syncthreads();
        const float* ks2 = kb + (size_t)kt * BK * DD;
        const float* vs = vb + (size_t)kt * BK * DD;

        #pragma unroll
        for (int it = 0; it < 2; ++it) {
            int c = tid + it * 256;
            int row = c >> 3, col8 = c & 7;
            f32x4 a  = *(const f32x4*)(ks2 + row * DD + col8 * 8);
            f32x4 bb = *(const f32x4*)(ks2 + row * DD + col8 * 8 + 4);
            s16x8 h, l;
            #pragma unroll
            for (int j = 0; j < 4; ++j) {
                uint16_t hh = f2bf(a[j]);
                h[j] = (short)hh; l[j] = (short)f2bf(a[j] - bf2f(hh));
                uint16_t hb = f2bf(bb[j]);
                h[4 + j] = (short)hb; l[4 + j] = (short)f2bf(bb[j] - bf2f(hb));
            }
            *(s16x8*)(lkh + swzb(row, col8 * 16)) = h;
            *(s16x8*)(lkl + swzb(row, col8 * 16)) = l;
        }
        #pragma unroll
        for (int it = 0; it < 8; ++it) {
            int c = tid + it * 256;
            int key = c >> 5, dp = (c & 31) * 2;
            f32x2 a = *(const f32x2*)(vs + key * DD + dp);
            *(uint16_t*)(lvt + swzb(dp,     key * 2)) = f2bf(a[0]);
            *(uint16_t*)(lvt + swzb(dp + 1, key * 2)) = f2bf(a[1]);
        }
        if (tid < BK) lmask[tid] = mb[kt * BK + tid];
        __syncthreads();

        f32x4 s[4];
        #pragma unroll
        for (int f = 0; f < 4; ++f) s[f] = (f32x4){0.f, 0.f, 0.f, 0.f};
        #pragma unroll
        for (int f = 0; f < 4; ++f) {
            #pragma unroll
            for (int kc = 0; kc < 2; ++kc) {
                s16x8 kfh = *(const s16x8*)(lkh + swzb(f * 16 + lm, kc * 64 + lg * 16));
                s16x8 kfl = *(const s16x8*)(lkl + swzb(f * 16 + lm, kc * 64 + lg * 16));
                s[f] = __builtin_amdgcn_mfma_f32_16x16x32_bf16(qfh[kc], kfh, s[f], 0, 0, 0);
                s[f] = __builtin_amdgcn_mfma_f32_16x16x32_bf16(qfh[kc], kfl, s[f], 0, 0, 0);
                s[f] = __builtin_amdgcn_mfma_f32_16x16x32_bf16(qfl[kc], kfh, s[f], 0, 0, 0);
            }
        }

        float mv[4];
        #pragma unroll
        for (int f = 0; f < 4; ++f) mv[f] = lmask[f * 16 + lm];

        float pmax[4];
        #pragma unroll
        for (int i = 0; i < 4; ++i) {
            float x = -1e30f;
            #pragma unroll
            for (int f = 0; f < 4; ++f) {
                float sv = (mv[f] != 0.f) ? s[f][i] : -1e30f;
                s[f][i] = sv;
                x = fmaxf(x, sv);
            }
            #pragma unroll
            for (int off = 1; off < 16; off <<= 1)
                x = fmaxf(x, __shfl_xor(x, off, 64));
            pmax[i] = x;
        }

        float scl[4];
        #pragma unroll
        for (int i = 0; i < 4; ++i) {
            float mn = fmaxf(mrow[i], pmax[i]);
            scl[i] = __expf(mrow[i] - mn);
            mrow[i] = mn;
        }
        float rs[4] = {0.f, 0.f, 0.f, 0.f};
        #pragma unroll
        for (int f = 0; f < 4; ++f) {
            #pragma unroll
            for (int i = 0; i < 4; ++i) {
                float p = __expf(s[f][i] - mrow[i]);
                s[f][i] = p;
                rs[i] += p;
            }
        }
        #pragma unroll
        for (int i = 0; i < 4; ++i) {
            #pragma unroll
            for (int off = 1; off < 16; off <<= 1)
                rs[i] += __shfl_xor(rs[i], off, 64);
            lrow[i] = lrow[i] * scl[i] + rs[i];
        }
        #pragma unroll
        for (int d = 0; d < 4; ++d)
            #pragma unroll
            for (int i = 0; i < 4; ++i)
                oacc[d][i] *= scl[i];

        #pragma unroll
        for (int f = 0; f < 4; ++f)
            #pragma unroll
            for (int i = 0; i < 4; ++i)
                *(uint16_t*)(lp + swzb(w * 16 + lg * 4 + i, (f * 16 + lm) * 2)) = f2bf(s[f][i]);
        __syncthreads();

        #pragma unroll
        for (int kc = 0; kc < 2; ++kc) {
            s16x8 pf = *(const s16x8*)(lp + swzb(w * 16 + lm, kc * 64 + lg * 16));
            #pragma unroll
            for (int d = 0; d < 4; ++d) {
                s16x8 vf = *(const s16x8*)(lvt + swzb(d * 16 + lm, kc * 64 + lg * 16));
                oacc[d] = __builtin_amdgcn_mfma_f32_16x16x32_bf16(pf, vf, oacc[d], 0, 0, 0);
            }
        }
    }

    float* ob = out + ((size_t)b * SLQ + (size_t)qt * BQ) * DD;
    #pragma unroll
    for (int i = 0; i < 4; ++i) {
        float inv = 1.f / (lrow[i] + 1e-13f);
        int row = w * 16 + lg * 4 + i;
        #pragma unroll
        for (int d = 0; d < 4; ++d)
            ob[row * DD + d * 16 + lm] = oacc[d][i] * inv;
    }
}

extern "C" void kernel_launch(void* const* d_in, const int* in_sizes, int n_in,
                              void* d_out, int out_size, void* d_ws, size_t ws_size,
                              hipStream_t stream) {
    const float* q  = (const float*)d_in[0];
    const float* k  = (const float*)d_in[1];
    const float* v  = (const float*)d_in[2];
    const float* vm = (const float*)d_in[3];
    float* out = (float*)d_out;

    const size_t tensor_bytes = (size_t)NB * SLK * DD * 2;   // 4 MB fp16
    if (ws_size < 3 * tensor_bytes) {
        dim3 grid(SLQ / BQ, NB);
        attn_fallback<<<grid, dim3(256), 0, stream>>>(q, k, v, vm, out);
        return;
    }

    char* qs  = (char*)d_ws;
    char* ks  = qs + tensor_bytes;
    char* vts = ks + tensor_bytes;

    prep_qk<<<dim3(1024), dim3(256), 0, stream>>>(q, k, qs, ks);
    prep_v <<<dim3(512),  dim3(256), 0, stream>>>(v, vts);
    attn_fwd<<<dim3(512), dim3(256), 0, stream>>>(qs, ks, vts, vm, out);
}

// Round 4
// 53.660 us; speedup vs baseline: 1.9580x; 1.5344x over previous
//
#include <hip/hip_runtime.h>
#include <hip/hip_bf16.h>
#include <stdint.h>

#define NB 16
#define SLQ 2048
#define SLK 2048
#define DD 64
#define BQ 64
#define BK 64
#define NT (SLK / BK)

typedef _Float16 f16x8 __attribute__((ext_vector_type(8)));
typedef short s16x8 __attribute__((ext_vector_type(8)));
typedef float f32x4 __attribute__((ext_vector_type(4)));
typedef float f32x2 __attribute__((ext_vector_type(2)));

typedef __attribute__((address_space(1))) const void gvoid;
typedef __attribute__((address_space(3))) void lvoid;

__device__ __forceinline__ int swzb(int row, int bytecol) {
    return row * 128 + (bytecol ^ ((row & 7) << 4));
}

__device__ __forceinline__ void gload16(const void* g, void* l) {
    __builtin_amdgcn_global_load_lds((gvoid*)g, (lvoid*)l, 16, 0, 0);
}

__device__ __forceinline__ uint16_t f2bf(float f) {
    __bf16 h = (__bf16)f;
    return __builtin_bit_cast(uint16_t, h);
}
__device__ __forceinline__ float bf2f(uint16_t u) {
    uint32_t x = ((uint32_t)u) << 16;
    return __builtin_bit_cast(float, x);
}

// ---------------- prep: Q,K f32 -> fp16 tiles (64x64, inverse-swizzled) ----------------
__global__ __launch_bounds__(256) void prep_qk(const float* __restrict__ q,
                                               const float* __restrict__ k,
                                               char* __restrict__ qs,
                                               char* __restrict__ ks) {
    const int tl = blockIdx.x & 511;
    const float* src = (blockIdx.x < 512 ? q : k) + (size_t)tl * (BK * DD);
    char* dst = (blockIdx.x < 512 ? qs : ks) + (size_t)tl * (BK * DD * 2);
    #pragma unroll
    for (int it = 0; it < 2; ++it) {
        int c = threadIdx.x + it * 256;
        int row = c >> 3, col8 = c & 7;
        f32x4 a  = *(const f32x4*)(src + row * DD + col8 * 8);
        f32x4 b2 = *(const f32x4*)(src + row * DD + col8 * 8 + 4);
        f16x8 h;
        #pragma unroll
        for (int j = 0; j < 4; ++j) { h[j] = (_Float16)a[j]; h[4 + j] = (_Float16)b2[j]; }
        *(f16x8*)(dst + swzb(row, col8 * 16)) = h;
    }
}

// ---------------- prep: V f32 -> bf16 transposed tiles [d][key] ----------------
__global__ __launch_bounds__(256) void prep_v(const float* __restrict__ v,
                                              char* __restrict__ vts) {
    const int tl = blockIdx.x;                 // 0..511
    const float* src = v + (size_t)tl * (BK * DD);
    char* dst = vts + (size_t)tl * (BK * DD * 2);
    const int d = threadIdx.x & 63;
    #pragma unroll
    for (int it = 0; it < 2; ++it) {
        int key8 = (threadIdx.x >> 6) + it * 4;
        s16x8 h;
        #pragma unroll
        for (int j = 0; j < 8; ++j)
            h[j] = (short)f2bf(src[(key8 * 8 + j) * DD + d]);
        *(s16x8*)(dst + swzb(d, key8 * 16)) = h;
    }
}

// ---------------- prep: mask -> additive bias ----------------
__global__ __launch_bounds__(256) void prep_bias(const float* __restrict__ vm,
                                                 float* __restrict__ bias2) {
    int i = blockIdx.x * 256 + threadIdx.x;
    bias2[i] = (vm[i] != 0.f) ? 0.f : -1e30f;
}

// ---------------- main flash-attn: fp16 QK, bf16 PV, no-max unnormalized softmax ----------------
__global__ __launch_bounds__(256, 4)
void attn_fwd(const char* __restrict__ qs, const char* __restrict__ ks,
              const char* __restrict__ vts, const float* __restrict__ bias2,
              float* __restrict__ po, float* __restrict__ pl,
              float* __restrict__ out, int ls)
{
    __shared__ __align__(16) char lp[BQ * DD * 2];        // Q stage, then P (bf16)
    __shared__ __align__(16) char lk[2][BK * DD * 2];     // fp16
    __shared__ __align__(16) char lv[2][BK * DD * 2];     // bf16

    const int tid  = threadIdx.x;
    const int lane = tid & 63;
    const int w    = tid >> 6;
    const int lg   = lane >> 4;
    const int lm   = lane & 15;

    const int G = 512 << ls;
    int wg = blockIdx.x;
    wg = (wg & 7) * (G >> 3) + (wg >> 3);      // XCD-chunked swizzle (G % 8 == 0)
    const int qt = wg & 31;
    const int rest = wg >> 5;
    const int sp = rest & ((1 << ls) - 1);
    const int b  = rest >> ls;
    const int NTE = NT >> ls;

    const char* qtile = qs  + (size_t)(b * 32 + qt) * 8192;
    const char* kbase = ks  + (size_t)(b * 32 + sp * NTE) * 8192;
    const char* vbase = vts + (size_t)(b * 32 + sp * NTE) * 8192;
    const float* mbias = bias2 + (size_t)b * SLK + sp * NTE * BK;

    // prologue: stage Q + tile 0
    #pragma unroll
    for (int i = 0; i < 2; ++i) {
        int ch = w * 2 + i;
        gload16(qtile + ch * 1024 + lane * 16, lp + ch * 1024);
    }
    #pragma unroll
    for (int i = 0; i < 2; ++i) {
        int ch = w * 2 + i;
        gload16(kbase + ch * 1024 + lane * 16, lk[0] + ch * 1024);
        gload16(vbase + ch * 1024 + lane * 16, lv[0] + ch * 1024);
    }
    asm volatile("s_waitcnt vmcnt(0)" ::: "memory");
    __syncthreads();

    f16x8 qf[2];
    #pragma unroll
    for (int kc = 0; kc < 2; ++kc)
        qf[kc] = *(const f16x8*)(lp + swzb(w * 16 + lm, kc * 64 + lg * 16));

    s16x8 ones;
    #pragma unroll
    for (int j = 0; j < 8; ++j) ones[j] = (short)0x3F80;   // bf16 1.0

    f32x4 oacc[4], rsacc;
    #pragma unroll
    for (int d = 0; d < 4; ++d) oacc[d] = (f32x4){0.f, 0.f, 0.f, 0.f};
    rsacc = (f32x4){0.f, 0.f, 0.f, 0.f};

    int buf = 0;
    for (int kt = 0; kt < NTE; ++kt) {
        // bias loads FIRST (older vmcnt entries than prefetch)
        float bv[4];
        #pragma unroll
        for (int f = 0; f < 4; ++f) bv[f] = mbias[kt * BK + f * 16 + lm];

        if (kt + 1 < NTE) {
            const char* kg = kbase + (size_t)(kt + 1) * 8192;
            const char* vg = vbase + (size_t)(kt + 1) * 8192;
            #pragma unroll
            for (int i = 0; i < 2; ++i) {
                int ch = w * 2 + i;
                gload16(kg + ch * 1024 + lane * 16, lk[buf ^ 1] + ch * 1024);
                gload16(vg + ch * 1024 + lane * 16, lv[buf ^ 1] + ch * 1024);
            }
        }

        // ---- S = Q K^T (fp16) ----
        f32x4 s[4];
        #pragma unroll
        for (int f = 0; f < 4; ++f) s[f] = (f32x4){0.f, 0.f, 0.f, 0.f};
        #pragma unroll
        for (int f = 0; f < 4; ++f) {
            #pragma unroll
            for (int kc = 0; kc < 2; ++kc) {
                f16x8 kf = *(const f16x8*)(lk[buf] + swzb(f * 16 + lm, kc * 64 + lg * 16));
                s[f] = __builtin_amdgcn_mfma_f32_16x16x32_f16(qf[kc], kf, s[f], 0, 0, 0);
            }
        }

        // ---- p = exp(s + bias), unnormalized; write P (bf16) to LDS ----
        #pragma unroll
        for (int f = 0; f < 4; ++f) {
            #pragma unroll
            for (int i = 0; i < 4; ++i) {
                float p = __expf(s[f][i] + bv[f]);
                *(uint16_t*)(lp + swzb(w * 16 + lg * 4 + i, (f * 16 + lm) * 2)) = f2bf(p);
            }
        }

        // ---- O += P V, rowsum += P * ones (bf16) ----
        #pragma unroll
        for (int kc = 0; kc < 2; ++kc) {
            s16x8 pf = *(const s16x8*)(lp + swzb(w * 16 + lm, kc * 64 + lg * 16));
            rsacc = __builtin_amdgcn_mfma_f32_16x16x32_bf16(pf, ones, rsacc, 0, 0, 0);
            #pragma unroll
            for (int d = 0; d < 4; ++d) {
                s16x8 vf = *(const s16x8*)(lv[buf] + swzb(d * 16 + lm, kc * 64 + lg * 16));
                oacc[d] = __builtin_amdgcn_mfma_f32_16x16x32_bf16(pf, vf, oacc[d], 0, 0, 0);
            }
        }

        asm volatile("s_waitcnt vmcnt(0)" ::: "memory");
        __syncthreads();
        buf ^= 1;
    }

    if (ls == 0) {
        float* ob = out + ((size_t)b * SLQ + (size_t)qt * BQ) * DD;
        #pragma unroll
        for (int i = 0; i < 4; ++i) {
            float inv = 1.f / (rsacc[i] + 1e-13f);
            int row = w * 16 + lg * 4 + i;
            #pragma unroll
            for (int d = 0; d < 4; ++d)
                ob[row * DD + d * 16 + lm] = oacc[d][i] * inv;
        }
    } else {
        float* pob = po + (size_t)wg * (BQ * DD);
        #pragma unroll
        for (int i = 0; i < 4; ++i) {
            int row = w * 16 + lg * 4 + i;
            #pragma unroll
            for (int d = 0; d < 4; ++d)
                pob[row * DD + d * 16 + lm] = oacc[d][i];
            if (lm == 0) pl[(size_t)wg * BQ + row] = rsacc[i];
        }
    }
}

// ---------------- merge (split-2): out = (O0+O1)/(l0+l1+eps) ----------------
__global__ __launch_bounds__(256)
void merge2(const float* __restrict__ po, const float* __restrict__ pl,
            float* __restrict__ out) {
    const int t  = blockIdx.x;        // 0..511 q-tiles
    const int b  = t >> 5, qt = t & 31;
    const int i0 = b * 64 + qt;       // (b*2+0)*32 + qt
    const int i1 = i0 + 32;
    const int r0 = threadIdx.x >> 4;
    const int c4 = (threadIdx.x & 15) * 4;
    const float* p0 = po + (size_t)i0 * (BQ * DD);
    const float* p1 = po + (size_t)i1 * (BQ * DD);
    float* ob = out + ((size_t)b * SLQ + (size_t)qt * BQ) * DD;
    #pragma unroll
    for (int rr = 0; rr < 64; rr += 16) {
        int r = r0 + rr;
        float l = pl[(size_t)i0 * BQ + r] + pl[(size_t)i1 * BQ + r] + 1e-13f;
        float inv = 1.f / l;
        f32x4 a = *(const f32x4*)(p0 + r * DD + c4);
        f32x4 c = *(const f32x4*)(p1 + r * DD + c4);
        f32x4 o;
        #pragma unroll
        for (int j = 0; j < 4; ++j) o[j] = (a[j] + c[j]) * inv;
        *(f32x4*)(ob + r * DD + c4) = o;
    }
}

// ---------------- fallback (round-2 proven kernel) ----------------
__global__ __launch_bounds__(256, 2)
void attn_fallback(const float* __restrict__ q, const float* __restrict__ k,
                   const float* __restrict__ v, const float* __restrict__ vm,
                   float* __restrict__ out)
{
    __shared__ __align__(16) char lqh[BQ * DD * 2];
    __shared__ __align__(16) char lql[BQ * DD * 2];
    __shared__ __align__(16) char lkh[BK * DD * 2];
    __shared__ __align__(16) char lkl[BK * DD * 2];
    __shared__ __align__(16) char lvt[DD * BK * 2];
    __shared__ __align__(16) char lp [BQ * BK * 2];
    __shared__ float lmask[BK];

    const int tid  = threadIdx.x;
    const int lane = tid & 63;
    const int w    = tid >> 6;
    const int lg   = lane >> 4;
    const int lm   = lane & 15;

    const int b  = blockIdx.y;
    const int qt = blockIdx.x;

    const float* qb = q + ((size_t)b * SLQ + (size_t)qt * BQ) * DD;
    const float* kb = k + (size_t)b * SLK * DD;
    const float* vb = v + (size_t)b * SLK * DD;
    const float* mb = vm + (size_t)b * SLK;

    #pragma unroll
    for (int it = 0; it < 2; ++it) {
        int c = tid + it * 256;
        int row = c >> 3, col8 = c & 7;
        f32x4 a  = *(const f32x4*)(qb + row * DD + col8 * 8);
        f32x4 bb = *(const f32x4*)(qb + row * DD + col8 * 8 + 4);
        s16x8 h, l;
        #pragma unroll
        for (int j = 0; j < 4; ++j) {
            uint16_t hh = f2bf(a[j]);
            h[j] = (short)hh; l[j] = (short)f2bf(a[j] - bf2f(hh));
            uint16_t hb = f2bf(bb[j]);
            h[4 + j] = (short)hb; l[4 + j] = (short)f2bf(bb[j] - bf2f(hb));
        }
        *(s16x8*)(lqh + swzb(row, col8 * 16)) = h;
        *(s16x8*)(lql + swzb(row, col8 * 16)) = l;
    }
    __syncthreads();

    s16x8 qfh[2], qfl[2];
    #pragma unroll
    for (int kc = 0; kc < 2; ++kc) {
        qfh[kc] = *(const s16x8*)(lqh + swzb(w * 16 + lm, kc * 64 + lg * 16));
        qfl[kc] = *(const s16x8*)(lql + swzb(w * 16 + lm, kc * 64 + lg * 16));
    }

    float mrow[4], lrow[4];
    f32x4 oacc[4];
    #pragma unroll
    for (int i = 0; i < 4; ++i) { mrow[i] = -1e30f; lrow[i] = 0.f; }
    #pragma unroll
    for (int d = 0; d < 4; ++d) oacc[d] = (f32x4){0.f, 0.f, 0.f, 0.f};

    for (int kt = 0; kt < NT; ++kt) {
        __syncthreads();
        const float* ks2 = kb + (size_t)kt * BK * DD;
        const float* vs = vb + (size_t)kt * BK * DD;

        #pragma unroll
        for (int it = 0; it < 2; ++it) {
            int c = tid + it * 256;
            int row = c >> 3, col8 = c & 7;
            f32x4 a  = *(const f32x4*)(ks2 + row * DD + col8 * 8);
            f32x4 bb = *(const f32x4*)(ks2 + row * DD + col8 * 8 + 4);
            s16x8 h, l;
            #pragma unroll
            for (int j = 0; j < 4; ++j) {
                uint16_t hh = f2bf(a[j]);
                h[j] = (short)hh; l[j] = (short)f2bf(a[j] - bf2f(hh));
                uint16_t hb = f2bf(bb[j]);
                h[4 + j] = (short)hb; l[4 + j] = (short)f2bf(bb[j] - bf2f(hb));
            }
            *(s16x8*)(lkh + swzb(row, col8 * 16)) = h;
            *(s16x8*)(lkl + swzb(row, col8 * 16)) = l;
        }
        #pragma unroll
        for (int it = 0; it < 8; ++it) {
            int c = tid + it * 256;
            int key = c >> 5, dp = (c & 31) * 2;
            f32x2 a = *(const f32x2*)(vs + key * DD + dp);
            *(uint16_t*)(lvt + swzb(dp,     key * 2)) = f2bf(a[0]);
            *(uint16_t*)(lvt + swzb(dp + 1, key * 2)) = f2bf(a[1]);
        }
        if (tid < BK) lmask[tid] = mb[kt * BK + tid];
        __syncthreads();

        f32x4 s[4];
        #pragma unroll
        for (int f = 0; f < 4; ++f) s[f] = (f32x4){0.f, 0.f, 0.f, 0.f};
        #pragma unroll
        for (int f = 0; f < 4; ++f) {
            #pragma unroll
            for (int kc = 0; kc < 2; ++kc) {
                s16x8 kfh = *(const s16x8*)(lkh + swzb(f * 16 + lm, kc * 64 + lg * 16));
                s16x8 kfl = *(const s16x8*)(lkl + swzb(f * 16 + lm, kc * 64 + lg * 16));
                s[f] = __builtin_amdgcn_mfma_f32_16x16x32_bf16(qfh[kc], kfh, s[f], 0, 0, 0);
                s[f] = __builtin_amdgcn_mfma_f32_16x16x32_bf16(qfh[kc], kfl, s[f], 0, 0, 0);
                s[f] = __builtin_amdgcn_mfma_f32_16x16x32_bf16(qfl[kc], kfh, s[f], 0, 0, 0);
            }
        }

        float mv[4];
        #pragma unroll
        for (int f = 0; f < 4; ++f) mv[f] = lmask[f * 16 + lm];

        float pmax[4];
        #pragma unroll
        for (int i = 0; i < 4; ++i) {
            float x = -1e30f;
            #pragma unroll
            for (int f = 0; f < 4; ++f) {
                float sv = (mv[f] != 0.f) ? s[f][i] : -1e30f;
                s[f][i] = sv;
                x = fmaxf(x, sv);
            }
            #pragma unroll
            for (int off = 1; off < 16; off <<= 1)
                x = fmaxf(x, __shfl_xor(x, off, 64));
            pmax[i] = x;
        }

        float scl[4];
        #pragma unroll
        for (int i = 0; i < 4; ++i) {
            float mn = fmaxf(mrow[i], pmax[i]);
            scl[i] = __expf(mrow[i] - mn);
            mrow[i] = mn;
        }
        float rs[4] = {0.f, 0.f, 0.f, 0.f};
        #pragma unroll
        for (int f = 0; f < 4; ++f) {
            #pragma unroll
            for (int i = 0; i < 4; ++i) {
                float p = __expf(s[f][i] - mrow[i]);
                s[f][i] = p;
                rs[i] += p;
            }
        }
        #pragma unroll
        for (int i = 0; i < 4; ++i) {
            #pragma unroll
            for (int off = 1; off < 16; off <<= 1)
                rs[i] += __shfl_xor(rs[i], off, 64);
            lrow[i] = lrow[i] * scl[i] + rs[i];
        }
        #pragma unroll
        for (int d = 0; d < 4; ++d)
            #pragma unroll
            for (int i = 0; i < 4; ++i)
                oacc[d][i] *= scl[i];

        #pragma unroll
        for (int f = 0; f < 4; ++f)
            #pragma unroll
            for (int i = 0; i < 4; ++i)
                *(uint16_t*)(lp + swzb(w * 16 + lg * 4 + i, (f * 16 + lm) * 2)) = f2bf(s[f][i]);
        __syncthreads();

        #pragma unroll
        for (int kc = 0; kc < 2; ++kc) {
            s16x8 pf = *(const s16x8*)(lp + swzb(w * 16 + lm, kc * 64 + lg * 16));
            #pragma unroll
            for (int d = 0; d < 4; ++d) {
                s16x8 vf = *(const s16x8*)(lvt + swzb(d * 16 + lm, kc * 64 + lg * 16));
                oacc[d] = __builtin_amdgcn_mfma_f32_16x16x32_bf16(pf, vf, oacc[d], 0, 0, 0);
            }
        }
    }

    float* ob = out + ((size_t)b * SLQ + (size_t)qt * BQ) * DD;
    #pragma unroll
    for (int i = 0; i < 4; ++i) {
        float inv = 1.f / (lrow[i] + 1e-13f);
        int row = w * 16 + lg * 4 + i;
        #pragma unroll
        for (int d = 0; d < 4; ++d)
            ob[row * DD + d * 16 + lm] = oacc[d][i] * inv;
    }
}

extern "C" void kernel_launch(void* const* d_in, const int* in_sizes, int n_in,
                              void* d_out, int out_size, void* d_ws, size_t ws_size,
                              hipStream_t stream) {
    const float* q  = (const float*)d_in[0];
    const float* k  = (const float*)d_in[1];
    const float* v  = (const float*)d_in[2];
    const float* vm = (const float*)d_in[3];
    float* out = (float*)d_out;

    const size_t TB   = (size_t)NB * SLK * DD * 2;        // 4 MB per fp16/bf16 tensor
    const size_t BIAS = (size_t)NB * SLK * 4;             // 128 KB
    const size_t PL   = (size_t)1024 * BQ * 4;            // 256 KB
    const size_t PO   = (size_t)1024 * BQ * DD * 4;       // 16 MB
    const size_t need_min   = 3 * TB + BIAS;
    const size_t need_split = need_min + PL + PO;

    if (ws_size < need_min) {
        dim3 grid(SLQ / BQ, NB);
        attn_fallback<<<grid, dim3(256), 0, stream>>>(q, k, v, vm, out);
        return;
    }

    char*  qs    = (char*)d_ws;
    char*  ks    = qs + TB;
    char*  vts   = ks + TB;
    float* bias2 = (float*)(vts + TB);
    float* pl    = (float*)((char*)bias2 + BIAS);
    float* po    = (float*)((char*)pl + PL);

    const int ls = (ws_size >= need_split) ? 1 : 0;

    prep_qk  <<<dim3(1024), dim3(256), 0, stream>>>(q, k, qs, ks);
    prep_v   <<<dim3(512),  dim3(256), 0, stream>>>(v, vts);
    prep_bias<<<dim3(NB * SLK / 256), dim3(256), 0, stream>>>(vm, bias2);
    attn_fwd <<<dim3(512 << ls), dim3(256), 0, stream>>>(qs, ks, vts, bias2, po, pl, out, ls);
    if (ls == 1)
        merge2<<<dim3(512), dim3(256), 0, stream>>>(po, pl, out);
}